// Round 4
// baseline (728.317 us; speedup 1.0000x reference)
//
#include <hip/hip_runtime.h>
#include <cstdint>

// Problem constants
#define T_ 64
#define A_ 48
#define NP_ 3072      // T*A pairs
#define E_ 22
#define RAW_ 512
#define H_ 256
#define NACT_ 21
#define NTP_ 3
#define PV_ 3456      // padded virtual pair rows (27 tiles of 128)
#define RV_ 68096     // padded virtual entity rows (532 tiles of 128)
#define NDEAD_ 67584  // NP_*E_

typedef unsigned short u16;
typedef unsigned int u32;
typedef __attribute__((ext_vector_type(8))) short short8;
typedef __attribute__((ext_vector_type(4))) short short4v;
typedef __attribute__((ext_vector_type(4))) float floatx4;

__device__ __forceinline__ u16 f2bf(float x) {
    unsigned u = __float_as_uint(x);
    unsigned r = (u + 0x7FFFu + ((u >> 16) & 1u)) >> 16;
    return (u16)r;
}
__device__ __forceinline__ float bf2f(u16 h) {
    return __uint_as_float(((unsigned)h) << 16);
}
// packed split: high16 = bf16(x), low16 = bf16(x - hi)
__device__ __forceinline__ u32 packsplit(float x) {
    u16 h = f2bf(x);
    u16 l = f2bf(x - bf2f(h));
    return (((u32)h) << 16) | l;
}

// ---------------------------------------------------------------------------
// K_bucket: sniff dead dtype, count pairs per type, build bucketed pair list.
// wsI layout: [0]=mode, [1..3]=cnt, [4..6]=ps, [8..10]=rs,
//             [16..16+PV)=pairIdx, then prb[PV]
// ---------------------------------------------------------------------------
__global__ void k_bucket(const unsigned* __restrict__ deadRaw,
                         const int* __restrict__ hete, int* __restrict__ wsI)
{
    __shared__ int fl[2];
    __shared__ int sc[3], cur[3], sps[3], srs[3];
    int tid = threadIdx.x;
    if (tid < 2) fl[tid] = 0;
    if (tid < 3) { sc[tid] = 0; cur[tid] = 0; }
    __syncthreads();
    int ni = 0, nf = 0;
    for (int i = tid; i < 1024; i += 256) {
        unsigned w = deadRaw[i];
        if (w > 1u) ni = 1;
        if (w != 0u && w != 0x3F800000u) nf = 1;
    }
    if (ni) atomicOr(&fl[0], 1);
    if (nf) atomicOr(&fl[1], 1);
    for (int p = tid; p < NP_; p += 256) atomicAdd(&sc[hete[p]], 1);
    __syncthreads();
    if (tid == 0) {
        int c0 = sc[0], c1 = sc[1], c2 = sc[2];
        int p1 = (c0 + 127) & ~127;
        int p2 = p1 + ((c1 + 127) & ~127);
        sps[0] = 0; sps[1] = p1; sps[2] = p2;
        int r1 = (22 * c0 + 127) & ~127;
        int r2 = r1 + ((22 * c1 + 127) & ~127);
        srs[0] = 0; srs[1] = r1; srs[2] = r2;
        wsI[0] = fl[0] ? (fl[1] ? 2 : 1) : 0;  // 0=int32,1=float32,2=byte
        wsI[1] = c0; wsI[2] = c1; wsI[3] = c2;
        wsI[4] = 0; wsI[5] = p1; wsI[6] = p2;
        wsI[8] = 0; wsI[9] = r1; wsI[10] = r2;
    }
    __syncthreads();
    int* pairIdx = wsI + 16;
    int* prb = pairIdx + PV_;
    for (int pv = tid; pv < PV_; pv += 256) pairIdx[pv] = -1;
    __syncthreads();
    for (int p = tid; p < NP_; p += 256) {
        int t = hete[p];
        int pos = atomicAdd(&cur[t], 1);
        pairIdx[sps[t] + pos] = p;
    }
    for (int pv = tid; pv < PV_; pv += 256) {
        int t = (pv >= sps[1]) + (pv >= sps[2]);
        prb[pv] = srs[t] + 22 * (pv - sps[t]);
    }
}

__global__ void k_deadmask(const void* __restrict__ dead,
                           const int* __restrict__ wsI, float* __restrict__ dm)
{
    int i = blockIdx.x * 256 + threadIdx.x;
    if (i >= NDEAD_) return;
    int mode = wsI[0];
    bool d;
    if (mode == 0)      d = ((const int*)dead)[i] != 0;
    else if (mode == 1) d = ((const float*)dead)[i] != 0.f;
    else                d = ((const unsigned char*)dead)[i] != 0;
    dm[i] = d ? 0.f : 1.f;
}

// rowObs[rv] = obs row index for virtual row, or -1 (padding OR dead -> zero A row)
__global__ void k_rowobs(const int* __restrict__ cnt, const int* __restrict__ ps,
                         const int* __restrict__ rs, const int* __restrict__ pairIdx,
                         const float* __restrict__ dm, int* __restrict__ rowObs)
{
    int rv = blockIdx.x * 256 + threadIdx.x;
    if (rv >= RV_) return;
    int t = (rv >= rs[1]) + (rv >= rs[2]);
    int local = rv - rs[t];
    int out = -1;
    if (local < 22 * cnt[t]) {
        int pl = local / 22;
        int e = local - pl * 22;
        int p = pairIdx[ps[t] + pl];
        if (p >= 0) {
            int oi = p * 22 + e;
            if (dm[oi] != 0.f) out = oi;
        }
    }
    rowObs[rv] = out;
}

// ---------------------------------------------------------------------------
// k_wconv: W[t][k][n] (fp32, n-width 256) -> WT_hi/WT_lo[t][n][k] (bf16 split)
// ---------------------------------------------------------------------------
__global__ void k_wconv(const float* __restrict__ W, u16* __restrict__ Hi,
                        u16* __restrict__ Lo, int K)
{
    int K8 = K >> 3;
    int kc = blockIdx.x % K8;
    int t  = blockIdx.x / K8;
    int n  = threadIdx.x;
    const float* w = W + (long)t * K * 256 + n;
    short8 hv, lv;
#pragma unroll
    for (int j = 0; j < 8; ++j) {
        float x = w[(long)(kc * 8 + j) * 256];
        u16 hh = f2bf(x);
        hv[j] = (short)hh;
        lv[j] = (short)f2bf(x - bf2f(hh));
    }
    long o = ((long)t * 256 + n) * K + kc * 8;
    *(short8*)(Hi + o) = hv;
    *(short8*)(Lo + o) = lv;
}

// ---------------------------------------------------------------------------
// MFMA GEMM via bf16x3 split. Tile 128x128, BK=32, 4 waves (each 64x64).
// A: AMODE 0 = fp32 + row-gather + mask (converted in-loop);
//    AMODE 1 = packed-split u32 (hi<<16|lo), unpacked with shifts.
// B: pre-split bf16 hi/lo [t][n][k], read DIRECTLY from global (L2-resident),
//    no LDS staging. Only A is staged in LDS (20.5 KB).
// OUTSPLIT: write C as packed-split u32 (feeds next GEMM); else fp32.
// Verified layouts (learn_hip m89/m120): A-frag A[m=lane&15][k=quad*8+j],
// B-frag B[k=quad*8+j][n=lane&15], D col=lane&15 row=quad*4+reg.
// ---------------------------------------------------------------------------
#define AST 40  // LDS row stride in shorts (32 k + 8 pad)
template<int AMODE, bool RELU, bool OUTSPLIT>
__global__ __launch_bounds__(256) void k_mgemm(
    const void* __restrict__ A0v, const void* __restrict__ A1v, int lda,
    const int* __restrict__ rowIdx,
    const u16* __restrict__ Bh0, const u16* __restrict__ Bl0,
    const u16* __restrict__ Bh1, const u16* __restrict__ Bl1,
    const float* __restrict__ bias0, const float* __restrict__ bias1,
    void* __restrict__ C0v, void* __restrict__ C1v, int ldc,
    int coff0, int coff1,
    const int* __restrict__ starts, int K)
{
    __shared__ short Ah[128 * AST], Al[128 * AST];

    const int tid = threadIdx.x;
    const int z = blockIdx.z;
    const void* Av = z ? A1v : A0v;
    const u16* Bhi = z ? Bh1 : Bh0;
    const u16* Blo = z ? Bl1 : Bl0;
    const float* bias = z ? bias1 : bias0;
    const int coff = z ? coff1 : coff0;

    const long rb = (long)blockIdx.x * 128;
    const int n0 = blockIdx.y * 128;
    const int t = (rb >= starts[0]) + (rb >= starts[1]);
    const u16* bhp = Bhi + ((long)t * 256 + n0) * K;
    const u16* blp = Blo + ((long)t * 256 + n0) * K;
    const float* biasT = bias + (long)t * 256 + n0;

    // ---- A loader setup ----
    // AMODE 0: 4 iters x (32 rows, float4); AMODE 1: 2 iters x (64 rows, 8xu32)
    const int ar0 = tid >> 3;           // 0..31  (AMODE 0)
    const int ac0 = (tid & 7) * 4;      // 0..28
    const int ar1 = tid >> 2;           // 0..63  (AMODE 1)
    const int ac1 = (tid & 3) * 8;      // 0..24
    long arow[4]; float amask[4];
    if (AMODE == 0) {
#pragma unroll
        for (int it = 0; it < 4; ++it) {
            int r = 32 * it + ar0;
            int i0 = rowIdx[rb + r];
            amask[it] = (i0 < 0) ? 0.f : 1.f;
            arow[it] = (i0 < 0) ? 0 : (long)i0 * lda;
        }
    } else {
#pragma unroll
        for (int it = 0; it < 2; ++it)
            arow[it] = (rb + 64 * it + ar1) * (long)lda;
    }

    // wave tiling
    const int wave = tid >> 6;
    const int lane = tid & 63;
    const int wr = (wave >> 1) * 64;
    const int wc = (wave & 1) * 64;
    const int lm = lane & 15;
    const int quad = lane >> 4;
    // per-wave B base (n = wc + 16j + lm, k = k0 + quad*8)
    const u16* bwh = bhp + (long)(wc + lm) * K + quad * 8;
    const u16* bwl = blp + (long)(wc + lm) * K + quad * 8;

    floatx4 acc[4][4];
#pragma unroll
    for (int i = 0; i < 4; ++i)
#pragma unroll
        for (int j = 0; j < 4; ++j) acc[i][j] = (floatx4){0.f, 0.f, 0.f, 0.f};

    for (int k0 = 0; k0 < K; k0 += 32) {
        // ---- stage A tile ----
        if (AMODE == 0) {
            const float* A = (const float*)Av;
            float4 av[4];
#pragma unroll
            for (int it = 0; it < 4; ++it)
                av[it] = *(const float4*)(A + arow[it] + k0 + ac0);
            __syncthreads();
#pragma unroll
            for (int it = 0; it < 4; ++it) {
                float xs[4] = {av[it].x, av[it].y, av[it].z, av[it].w};
                short4v hv, lv;
#pragma unroll
                for (int e = 0; e < 4; ++e) {
                    float x = xs[e] * amask[it];
                    u16 hh = f2bf(x);
                    hv[e] = (short)hh;
                    lv[e] = (short)f2bf(x - bf2f(hh));
                }
                int r = 32 * it + ar0;
                *(short4v*)&Ah[r * AST + ac0] = hv;
                *(short4v*)&Al[r * AST + ac0] = lv;
            }
        } else {
            const u32* A = (const u32*)Av;
            uint4 u0[2], u1[2];
#pragma unroll
            for (int it = 0; it < 2; ++it) {
                u0[it] = *(const uint4*)(A + arow[it] + k0 + ac1);
                u1[it] = *(const uint4*)(A + arow[it] + k0 + ac1 + 4);
            }
            __syncthreads();
#pragma unroll
            for (int it = 0; it < 2; ++it) {
                u32 w[8] = {u0[it].x, u0[it].y, u0[it].z, u0[it].w,
                            u1[it].x, u1[it].y, u1[it].z, u1[it].w};
                short8 hv, lv;
#pragma unroll
                for (int e = 0; e < 8; ++e) {
                    hv[e] = (short)(w[e] >> 16);
                    lv[e] = (short)(w[e] & 0xFFFFu);
                }
                int r = 64 * it + ar1;
                *(short8*)&Ah[r * AST + ac1] = hv;
                *(short8*)&Al[r * AST + ac1] = lv;
            }
        }
        __syncthreads();

        // ---- B fragments straight from global (L2) ----
        short8 fbh[4], fbl[4];
#pragma unroll
        for (int j = 0; j < 4; ++j) {
            long o = (long)(16 * j) * K + k0;
            fbh[j] = *(const short8*)(bwh + o);
            fbl[j] = *(const short8*)(bwl + o);
        }
        // ---- A fragments from LDS ----
        short8 fah[4], fal[4];
#pragma unroll
        for (int i = 0; i < 4; ++i) {
            int m = wr + 16 * i + lm;
            fah[i] = *(const short8*)&Ah[m * AST + quad * 8];
            fal[i] = *(const short8*)&Al[m * AST + quad * 8];
        }
        // ---- MFMA ----
#pragma unroll
        for (int j = 0; j < 4; ++j) {
#pragma unroll
            for (int i = 0; i < 4; ++i) {
                acc[i][j] = __builtin_amdgcn_mfma_f32_16x16x32_bf16(fah[i], fbh[j], acc[i][j], 0, 0, 0);
                acc[i][j] = __builtin_amdgcn_mfma_f32_16x16x32_bf16(fal[i], fbh[j], acc[i][j], 0, 0, 0);
                acc[i][j] = __builtin_amdgcn_mfma_f32_16x16x32_bf16(fah[i], fbl[j], acc[i][j], 0, 0, 0);
            }
        }
    }
    // ---- epilogue ----
#pragma unroll
    for (int j = 0; j < 4; ++j) {
        int col = wc + 16 * j + lm;
        float bj = biasT[col];
#pragma unroll
        for (int i = 0; i < 4; ++i) {
            long rbase = rb + wr + 16 * i + quad * 4;
#pragma unroll
            for (int r = 0; r < 4; ++r) {
                float vv = acc[i][j][r] + bj;
                if (RELU) vv = fmaxf(vv, 0.f);
                long o = (rbase + r) * (long)ldc + coff + n0 + col;
                if (OUTSPLIT) ((u32*)(z ? C1v : C0v))[o] = packsplit(vv);
                else          ((float*)(z ? C1v : C0v))[o] = vv;
            }
        }
    }
}

// ---------------------------------------------------------------------------
// k_prep: per pair — denom, v-pool, z-pool, assemble XF/XH (1536 each),
// written in packed-split u32 format for the head GEMMs.
// XF = [vs, poolf, zs(512), poolzf(512)], XH = [vs, poolh, zs, poolzh]
// ---------------------------------------------------------------------------
__global__ __launch_bounds__(256) void k_prep(
    const int* __restrict__ pairIdx, const int* __restrict__ prb,
    const float* __restrict__ dm, const float* __restrict__ v,
    const float* __restrict__ obs,
    u32* __restrict__ XF, u32* __restrict__ XH)
{
    int pv = blockIdx.x, c = threadIdx.x;
    int p = pairIdx[pv];
    u32* xf = XF + (long)pv * 1536;
    u32* xh = XH + (long)pv * 1536;
    if (p < 0) {
        for (int s = 0; s < 6; ++s) { xf[s * 256 + c] = 0u; xh[s * 256 + c] = 0u; }
        return;
    }
    __shared__ float sw[22];
    if (c < 22) sw[c] = dm[p * 22 + c];
    __syncthreads();
    float denf = 0.f, denh = 0.f;
    for (int e = 1; e < 12; ++e)  denf += sw[e];
    for (int e = 12; e < 22; ++e) denh += sw[e];
    denf = 1.f / fmaxf(denf, 1.f);
    denh = 1.f / fmaxf(denh, 1.f);

    long base = prb[pv];
    u32 vs = packsplit(v[base * 256 + c]);
    xf[c] = vs; xh[c] = vs;
    float af = 0.f, ah = 0.f;
    for (int e = 1; e < 12; ++e)  af += sw[e] * v[(base + e) * 256 + c];
    for (int e = 12; e < 22; ++e) ah += sw[e] * v[(base + e) * 256 + c];
    xf[256 + c] = packsplit(af * denf);
    xh[256 + c] = packsplit(ah * denh);
    const float* ob = obs + (long)p * 22 * 512;
    float w0 = sw[0];
    u32 z0 = packsplit(ob[c] * w0);
    u32 z1 = packsplit(ob[256 + c] * w0);
    xf[512 + c] = z0; xh[512 + c] = z0;
    xf[768 + c] = z1; xh[768 + c] = z1;
#pragma unroll
    for (int half = 0; half < 2; ++half) {
        int c2 = c + half * 256;
        float zf = 0.f, zh = 0.f;
        for (int e = 1; e < 12; ++e)  zf += sw[e] * ob[(long)e * 512 + c2];
        for (int e = 12; e < 22; ++e) zh += sw[e] * ob[(long)e * 512 + c2];
        xf[1024 + c2] = packsplit(zf * denf);
        xh[1024 + c2] = packsplit(zh * denh);
    }
}

// ---------------------------------------------------------------------------
// Final: L2 layer fused + logits + argmax + log-softmax + value dot; scatter.
// ---------------------------------------------------------------------------
__global__ __launch_bounds__(128) void k_final(
    const float* __restrict__ g1, const float* __restrict__ vV,
    const float* __restrict__ L2, const float* __restrict__ bL2,
    const float* __restrict__ L3, const float* __restrict__ bL3,
    const float* __restrict__ V2, const float* __restrict__ bV2,
    const int* __restrict__ pairIdx, const int* __restrict__ ps,
    float* __restrict__ out)
{
    int pv = blockIdx.x;
    int p = pairIdx[pv];
    if (p < 0) return;
    int c = threadIdx.x;
    int t = (pv >= ps[1]) + (pv >= ps[2]);

    __shared__ float sg1[256], sg2[128], sval[2];
    const float* g1p = g1 + (long)pv * 256;
    sg1[c] = g1p[c];
    sg1[c + 128] = g1p[c + 128];

    const float* vv = vV + (long)pv * 256;
    const float* v2t = V2 + t * 256;
    float s = vv[c] * v2t[c] + vv[c + 128] * v2t[c + 128];
    for (int off = 32; off; off >>= 1) s += __shfl_down(s, off);
    if ((c & 63) == 0) sval[c >> 6] = s;
    __syncthreads();

    const float* l2 = L2 + (long)t * 256 * 128 + c;
    float a = bL2[t * 128 + c];
#pragma unroll 8
    for (int k = 0; k < 256; ++k) a = fmaf(sg1[k], l2[(long)k * 128], a);
    sg2[c] = fmaxf(a, 0.f);
    __syncthreads();

    if (c < 64) {
        float lg = -3.0e38f;
        if (c < 21) {
            const float* l3t = L3 + (long)t * 128 * 21 + c;
            float acc = bL3[t * 21 + c];
            for (int k = 0; k < 128; ++k) acc = fmaf(sg2[k], l3t[k * 21], acc);
            lg = acc;
        }
        float mv = lg; int mi = (c < 21) ? c : 9999;
        for (int off = 32; off; off >>= 1) {
            float ov = __shfl_down(mv, off);
            int oi = __shfl_down(mi, off);
            if (ov > mv || (ov == mv && oi < mi)) { mv = ov; mi = oi; }
        }
        mv = __shfl(mv, 0); mi = __shfl(mi, 0);
        float e = (c < 21) ? expf(lg - mv) : 0.f;
        for (int off = 32; off; off >>= 1) e += __shfl_down(e, off);
        if (c == 0) {
            out[p] = (float)mi;
            out[NP_ + p] = sval[0] + sval[1] + bV2[t];
            out[2 * NP_ + p] = -logf(e);
        }
    }
}

// ---------------------------------------------------------------------------
extern "C" void kernel_launch(void* const* d_in, const int* in_sizes, int n_in,
                              void* d_out, int out_size, void* d_ws, size_t ws_size,
                              hipStream_t stream)
{
    const float* obs = (const float*)d_in[0];
    const int* hete = (const int*)d_in[1];
    const void* dead = d_in[2];
    const float* W1 = (const float*)d_in[3];  const float* b1 = (const float*)d_in[4];
    const float* W2 = (const float*)d_in[5];  const float* b2 = (const float*)d_in[6];
    const float* WCf = (const float*)d_in[7]; const float* bCf = (const float*)d_in[8];
    const float* WMf = (const float*)d_in[9]; const float* bMf = (const float*)d_in[10];
    const float* WCh = (const float*)d_in[11]; const float* bCh = (const float*)d_in[12];
    const float* WMh = (const float*)d_in[13]; const float* bMh = (const float*)d_in[14];
    const float* L1 = (const float*)d_in[15]; const float* bL1 = (const float*)d_in[16];
    const float* L2 = (const float*)d_in[17]; const float* bL2 = (const float*)d_in[18];
    const float* L3 = (const float*)d_in[19]; const float* bL3 = (const float*)d_in[20];
    const float* V1 = (const float*)d_in[21]; const float* bV1 = (const float*)d_in[22];
    const float* V2 = (const float*)d_in[23]; const float* bV2 = (const float*)d_in[24];
    float* out = (float*)d_out;

    // ---- workspace carve-up ----
    int* wsI = (int*)d_ws;
    int* pairIdx = wsI + 16;
    int* prb = pairIdx + PV_;
    int* rowObs = prb + PV_;
    long fbase = ((16L + PV_ + PV_ + RV_) + 63) & ~63L;
    float* wsF = (float*)d_ws;
    float* dm = wsF + fbase;
    float* cur = dm + NDEAD_;
    // bf16-split transposed weights (hi/lo per matrix)
    auto allocUS = [&](long K) { u16* p = (u16*)cur; cur += (3L * 256 * K) / 2; return p; };
    u16* W1h = allocUS(512);  u16* W1l = allocUS(512);
    u16* W2h = allocUS(256);  u16* W2l = allocUS(256);
    u16* WCfh = allocUS(512); u16* WCfl = allocUS(512);
    u16* WChh = allocUS(512); u16* WChl = allocUS(512);
    u16* WMfh = allocUS(1536); u16* WMfl = allocUS(1536);
    u16* WMhh = allocUS(1536); u16* WMhl = allocUS(1536);
    u16* L1h = allocUS(512);  u16* L1l = allocUS(512);
    u16* V1h = allocUS(512);  u16* V1l = allocUS(512);
    float* regA = cur;                               // RV_*256 floats
    float* regB = regA + (long)RV_ * 256;            // RV_*256 floats
    u32* h1p = (u32*)regA;                           // packed h1; then XF/XH overlay
    u32* XFp = (u32*)regA;
    u32* XHp = XFp + (long)PV_ * 1536;
    float* v = regB;                                 // fp32; then head overlay
    u32* vCp = (u32*)regB;
    u32* vMp = vCp + (long)PV_ * 512;
    float* g1 = (float*)(vMp + (long)PV_ * 512);
    float* vV = g1 + (long)PV_ * 256;

    // ---- bookkeeping ----
    k_bucket<<<1, 256, 0, stream>>>((const unsigned*)dead, hete, wsI);
    k_deadmask<<<264, 256, 0, stream>>>(dead, wsI, dm);
    k_rowobs<<<266, 256, 0, stream>>>(wsI + 1, wsI + 4, wsI + 8, pairIdx, dm, rowObs);

    // ---- weight conversion (transpose + bf16 hi/lo split) ----
    k_wconv<<<3 * 512 / 8, 256, 0, stream>>>(W1, W1h, W1l, 512);
    k_wconv<<<3 * 256 / 8, 256, 0, stream>>>(W2, W2h, W2l, 256);
    k_wconv<<<3 * 512 / 8, 256, 0, stream>>>(WCf, WCfh, WCfl, 512);
    k_wconv<<<3 * 512 / 8, 256, 0, stream>>>(WCh, WChh, WChl, 512);
    k_wconv<<<3 * 1536 / 8, 256, 0, stream>>>(WMf, WMfh, WMfl, 1536);
    k_wconv<<<3 * 1536 / 8, 256, 0, stream>>>(WMh, WMhh, WMhl, 1536);
    k_wconv<<<3 * 512 / 8, 256, 0, stream>>>(L1, L1h, L1l, 512);
    k_wconv<<<3 * 512 / 8, 256, 0, stream>>>(V1, V1h, V1l, 512);

    // ---- phase 1 (entity rows, bucketed by type) ----
    // gemm1: h1p = relu(obs@W1+b1)  [packed out]
    k_mgemm<0, true, true><<<dim3(RV_ / 128, 2, 1), 256, 0, stream>>>(
        obs, obs, 512, rowObs, W1h, W1l, W1h, W1l, b1, b1,
        h1p, h1p, 256, 0, 0, wsI + 9, 512);
    // gemm2: v = h1@W2+b2  [fp32 out, feeds k_prep]
    k_mgemm<1, false, false><<<dim3(RV_ / 128, 2, 1), 256, 0, stream>>>(
        h1p, h1p, 256, nullptr, W2h, W2l, W2h, W2l, b2, b2,
        v, v, 256, 0, 0, wsI + 9, 256);

    // ---- pair prep (writes packed XF/XH) ----
    k_prep<<<PV_, 256, 0, stream>>>(pairIdx, prb, dm, v, obs, XFp, XHp);

    // ---- heads (z-batched pairs) ----
    // H1: vC = [relu(XF@WCf) | relu(XH@WCh)]   K=512, packed out
    k_mgemm<1, true, true><<<dim3(PV_ / 128, 2, 2), 256, 0, stream>>>(
        XFp, XHp, 1536, nullptr, WCfh, WCfl, WChh, WChl, bCf, bCh,
        vCp, vCp, 512, 0, 256, wsI + 5, 512);
    // H2: vM = [relu(XF@WMf) | relu(XH@WMh)]   K=1536, packed out
    k_mgemm<1, true, true><<<dim3(PV_ / 128, 2, 2), 256, 0, stream>>>(
        XFp, XHp, 1536, nullptr, WMfh, WMfl, WMhh, WMhl, bMf, bMh,
        vMp, vMp, 512, 0, 256, wsI + 5, 1536);
    // H3: g1 = relu(vC@L1); vV = relu(vM@V1)   K=512, fp32 out
    k_mgemm<1, true, false><<<dim3(PV_ / 128, 2, 2), 256, 0, stream>>>(
        vCp, vMp, 512, nullptr, L1h, L1l, V1h, V1l, bL1, bV1,
        g1, vV, 256, 0, 0, wsI + 5, 512);

    k_final<<<PV_, 128, 0, stream>>>(g1, vV, L2, bL2, L3, bL3, V2, bV2,
                                     pairIdx, wsI + 4, out);
    (void)in_sizes; (void)n_in; (void)out_size; (void)ws_size;
}

// Round 5
// 703.265 us; speedup vs baseline: 1.0356x; 1.0356x over previous
//
#include <hip/hip_runtime.h>
#include <cstdint>

// Problem constants
#define T_ 64
#define A_ 48
#define NP_ 3072      // T*A pairs
#define E_ 22
#define RAW_ 512
#define H_ 256
#define NACT_ 21
#define NTP_ 3
#define PV_ 3456      // padded virtual pair rows (27 tiles of 128)
#define RV_ 68096     // padded virtual entity rows (532 tiles of 128)
#define NDEAD_ 67584  // NP_*E_

typedef unsigned short u16;
typedef unsigned int u32;
typedef __attribute__((ext_vector_type(8))) short short8;
typedef __attribute__((ext_vector_type(4))) short short4v;
typedef __attribute__((ext_vector_type(4))) float floatx4;

__device__ __forceinline__ u16 f2bf(float x) {
    unsigned u = __float_as_uint(x);
    unsigned r = (u + 0x7FFFu + ((u >> 16) & 1u)) >> 16;
    return (u16)r;
}
__device__ __forceinline__ float bf2f(u16 h) {
    return __uint_as_float(((unsigned)h) << 16);
}
// packed split: high16 = bf16(x), low16 = bf16(x - hi)
__device__ __forceinline__ u32 packsplit(float x) {
    u16 h = f2bf(x);
    u16 l = f2bf(x - bf2f(h));
    return (((u32)h) << 16) | l;
}

// ---------------------------------------------------------------------------
// K_bucket: sniff dead dtype, count pairs per type, build bucketed pair list.
// wsI layout: [0]=mode, [1..3]=cnt, [4..6]=ps, [8..10]=rs,
//             [16..16+PV)=pairIdx, then prb[PV]
// ---------------------------------------------------------------------------
__global__ void k_bucket(const unsigned* __restrict__ deadRaw,
                         const int* __restrict__ hete, int* __restrict__ wsI)
{
    __shared__ int fl[2];
    __shared__ int sc[3], cur[3], sps[3], srs[3];
    int tid = threadIdx.x;
    if (tid < 2) fl[tid] = 0;
    if (tid < 3) { sc[tid] = 0; cur[tid] = 0; }
    __syncthreads();
    int ni = 0, nf = 0;
    for (int i = tid; i < 1024; i += 256) {
        unsigned w = deadRaw[i];
        if (w > 1u) ni = 1;
        if (w != 0u && w != 0x3F800000u) nf = 1;
    }
    if (ni) atomicOr(&fl[0], 1);
    if (nf) atomicOr(&fl[1], 1);
    for (int p = tid; p < NP_; p += 256) atomicAdd(&sc[hete[p]], 1);
    __syncthreads();
    if (tid == 0) {
        int c0 = sc[0], c1 = sc[1], c2 = sc[2];
        int p1 = (c0 + 127) & ~127;
        int p2 = p1 + ((c1 + 127) & ~127);
        sps[0] = 0; sps[1] = p1; sps[2] = p2;
        int r1 = (22 * c0 + 127) & ~127;
        int r2 = r1 + ((22 * c1 + 127) & ~127);
        srs[0] = 0; srs[1] = r1; srs[2] = r2;
        wsI[0] = fl[0] ? (fl[1] ? 2 : 1) : 0;  // 0=int32,1=float32,2=byte
        wsI[1] = c0; wsI[2] = c1; wsI[3] = c2;
        wsI[4] = 0; wsI[5] = p1; wsI[6] = p2;
        wsI[8] = 0; wsI[9] = r1; wsI[10] = r2;
    }
    __syncthreads();
    int* pairIdx = wsI + 16;
    int* prb = pairIdx + PV_;
    for (int pv = tid; pv < PV_; pv += 256) pairIdx[pv] = -1;
    __syncthreads();
    for (int p = tid; p < NP_; p += 256) {
        int t = hete[p];
        int pos = atomicAdd(&cur[t], 1);
        pairIdx[sps[t] + pos] = p;
    }
    for (int pv = tid; pv < PV_; pv += 256) {
        int t = (pv >= sps[1]) + (pv >= sps[2]);
        prb[pv] = srs[t] + 22 * (pv - sps[t]);
    }
}

__global__ void k_deadmask(const void* __restrict__ dead,
                           const int* __restrict__ wsI, float* __restrict__ dm)
{
    int i = blockIdx.x * 256 + threadIdx.x;
    if (i >= NDEAD_) return;
    int mode = wsI[0];
    bool d;
    if (mode == 0)      d = ((const int*)dead)[i] != 0;
    else if (mode == 1) d = ((const float*)dead)[i] != 0.f;
    else                d = ((const unsigned char*)dead)[i] != 0;
    dm[i] = d ? 0.f : 1.f;
}

// rowObs[rv] = obs row index for virtual row, or -1 (padding OR dead -> zero A row)
__global__ void k_rowobs(const int* __restrict__ cnt, const int* __restrict__ ps,
                         const int* __restrict__ rs, const int* __restrict__ pairIdx,
                         const float* __restrict__ dm, int* __restrict__ rowObs)
{
    int rv = blockIdx.x * 256 + threadIdx.x;
    if (rv >= RV_) return;
    int t = (rv >= rs[1]) + (rv >= rs[2]);
    int local = rv - rs[t];
    int out = -1;
    if (local < 22 * cnt[t]) {
        int pl = local / 22;
        int e = local - pl * 22;
        int p = pairIdx[ps[t] + pl];
        if (p >= 0) {
            int oi = p * 22 + e;
            if (dm[oi] != 0.f) out = oi;
        }
    }
    rowObs[rv] = out;
}

// ---------------------------------------------------------------------------
// k_wconv: W[t][k][n] (fp32, n-width 256) -> fragment-ordered bf16 hi/lo:
//   Hi[((t*Kg + g)*256 + n)*8 + e]  with g = k/8, e = k%8, Kg = K/8.
// A wave's B-fragment load (lane l: n = base + (l&15), k-group = g0 + (l>>4))
// then reads 4 contiguous 256B segments -> fully coalesced, no LDS needed.
// ---------------------------------------------------------------------------
__global__ void k_wconv(const float* __restrict__ W, u16* __restrict__ Hi,
                        u16* __restrict__ Lo, int K)
{
    int Kg = K >> 3;
    int g = blockIdx.x % Kg;
    int t = blockIdx.x / Kg;
    int n = threadIdx.x;
    const float* w = W + (long)t * K * 256 + n;
    short8 hv, lv;
#pragma unroll
    for (int j = 0; j < 8; ++j) {
        float x = w[(long)(g * 8 + j) * 256];
        u16 hh = f2bf(x);
        hv[j] = (short)hh;
        lv[j] = (short)f2bf(x - bf2f(hh));
    }
    long o = (((long)t * Kg + g) * 256 + n) * 8;
    *(short8*)(Hi + o) = hv;
    *(short8*)(Lo + o) = lv;
}

// ---------------------------------------------------------------------------
// MFMA GEMM via bf16x3 split. Block = 4 waves (2x2), wave tile FI*16 x FJ*16,
// block tile (FI*32) x (FJ*32). BK=32.
// A: AMODE 0 = fp32 + row-gather + mask (converted in-loop);
//    AMODE 1 = packed-split u32. A staged in LDS (hi/lo shorts).
// B: fragment-ordered bf16 hi/lo (k_wconv layout), read straight from L2 —
//    coalesced 4-segment wave loads, zero LDS.
// OUTSPLIT: write C packed-split u32; else fp32.
// Layouts (m89/m120): A[m=lane&15][k=quad*8+j], B[k=quad*8+j][n=lane&15],
// D col=lane&15 row=quad*4+reg.
// ---------------------------------------------------------------------------
#define AST 40  // LDS row stride in shorts (32 k + 8 pad)
template<int AMODE, bool RELU, bool OUTSPLIT, int FI, int FJ>
__global__ __launch_bounds__(256) void k_mgemm(
    const void* __restrict__ A0v, const void* __restrict__ A1v, int lda,
    const int* __restrict__ rowIdx,
    const u16* __restrict__ Bh0, const u16* __restrict__ Bl0,
    const u16* __restrict__ Bh1, const u16* __restrict__ Bl1,
    const float* __restrict__ bias0, const float* __restrict__ bias1,
    void* __restrict__ C0v, void* __restrict__ C1v, int ldc,
    int coff0, int coff1,
    const int* __restrict__ starts, int K)
{
    constexpr int R = FI * 32;                 // block rows
    __shared__ short Ah[R * AST], Al[R * AST];

    const int tid = threadIdx.x;
    const int z = blockIdx.z;
    const void* Av = z ? A1v : A0v;
    const u16* Bhi = z ? Bh1 : Bh0;
    const u16* Blo = z ? Bl1 : Bl0;
    const float* bias = z ? bias1 : bias0;
    const int coff = z ? coff1 : coff0;

    const long rb = (long)blockIdx.x * R;
    const int n0 = blockIdx.y * (FJ * 32);
    const int t = (rb >= starts[0]) + (rb >= starts[1]);
    const int Kg = K >> 3;
    const float* biasT = bias + (long)t * 256 + n0;

    // wave tiling
    const int wave = tid >> 6;
    const int lane = tid & 63;
    const int wr = (wave >> 1) * (FI * 16);
    const int wc = (wave & 1) * (FJ * 16);
    const int lm = lane & 15;
    const int quad = lane >> 4;
    // fragment-ordered B base for this wave/lane
    const u16* bwh = Bhi + (((long)t * Kg + quad) * 256 + n0 + wc + lm) * 8;
    const u16* bwl = Blo + (((long)t * Kg + quad) * 256 + n0 + wc + lm) * 8;

    // ---- A loader setup ----
    const int ar0 = tid >> 3;           // 0..31  (AMODE 0, 32 rows/iter)
    const int ac0 = (tid & 7) * 4;
    const int ar1 = tid >> 2;           // 0..63  (AMODE 1, 64 rows/iter)
    const int ac1 = (tid & 3) * 8;
    long arow[4]; float amask[4];
    if (AMODE == 0) {
#pragma unroll
        for (int it = 0; it < FI; ++it) {
            int r = 32 * it + ar0;
            int i0 = rowIdx[rb + r];
            amask[it] = (i0 < 0) ? 0.f : 1.f;
            arow[it] = (i0 < 0) ? 0 : (long)i0 * lda;
        }
    } else {
#pragma unroll
        for (int it = 0; it < FI / 2; ++it)
            arow[it] = (rb + 64 * it + ar1) * (long)lda;
    }

    floatx4 acc[FI][FJ];
#pragma unroll
    for (int i = 0; i < FI; ++i)
#pragma unroll
        for (int j = 0; j < FJ; ++j) acc[i][j] = (floatx4){0.f, 0.f, 0.f, 0.f};

    for (int k0 = 0; k0 < K; k0 += 32) {
        // ---- stage A tile in LDS (hi/lo shorts) ----
        if (AMODE == 0) {
            const float* A = (const float*)Av;
            float4 av[FI];
#pragma unroll
            for (int it = 0; it < FI; ++it)
                av[it] = *(const float4*)(A + arow[it] + k0 + ac0);
            __syncthreads();
#pragma unroll
            for (int it = 0; it < FI; ++it) {
                float xs[4] = {av[it].x, av[it].y, av[it].z, av[it].w};
                short4v hv, lv;
#pragma unroll
                for (int e = 0; e < 4; ++e) {
                    float x = xs[e] * amask[it];
                    u16 hh = f2bf(x);
                    hv[e] = (short)hh;
                    lv[e] = (short)f2bf(x - bf2f(hh));
                }
                int r = 32 * it + ar0;
                *(short4v*)&Ah[r * AST + ac0] = hv;
                *(short4v*)&Al[r * AST + ac0] = lv;
            }
        } else {
            const u32* A = (const u32*)Av;
            uint4 u0[FI / 2], u1[FI / 2];
#pragma unroll
            for (int it = 0; it < FI / 2; ++it) {
                u0[it] = *(const uint4*)(A + arow[it] + k0 + ac1);
                u1[it] = *(const uint4*)(A + arow[it] + k0 + ac1 + 4);
            }
            __syncthreads();
#pragma unroll
            for (int it = 0; it < FI / 2; ++it) {
                u32 w[8] = {u0[it].x, u0[it].y, u0[it].z, u0[it].w,
                            u1[it].x, u1[it].y, u1[it].z, u1[it].w};
                short8 hv, lv;
#pragma unroll
                for (int e = 0; e < 8; ++e) {
                    hv[e] = (short)(w[e] >> 16);
                    lv[e] = (short)(w[e] & 0xFFFFu);
                }
                int r = 64 * it + ar1;
                *(short8*)&Ah[r * AST + ac1] = hv;
                *(short8*)&Al[r * AST + ac1] = lv;
            }
        }
        __syncthreads();

        // ---- A fragments from LDS ----
        short8 fah[FI], fal[FI];
#pragma unroll
        for (int i = 0; i < FI; ++i) {
            int m = wr + 16 * i + lm;
            fah[i] = *(const short8*)&Ah[m * AST + quad * 8];
            fal[i] = *(const short8*)&Al[m * AST + quad * 8];
        }
        // ---- B fragments from L2 (coalesced), MFMA ----
        const long gb = ((long)(k0 >> 3)) * 2048;   // (k0/8)*256*8 shorts
#pragma unroll
        for (int j = 0; j < FJ; ++j) {
            short8 fbh = *(const short8*)(bwh + gb + j * 128);
            short8 fbl = *(const short8*)(bwl + gb + j * 128);
#pragma unroll
            for (int i = 0; i < FI; ++i) {
                acc[i][j] = __builtin_amdgcn_mfma_f32_16x16x32_bf16(fah[i], fbh, acc[i][j], 0, 0, 0);
                acc[i][j] = __builtin_amdgcn_mfma_f32_16x16x32_bf16(fal[i], fbh, acc[i][j], 0, 0, 0);
                acc[i][j] = __builtin_amdgcn_mfma_f32_16x16x32_bf16(fah[i], fbl, acc[i][j], 0, 0, 0);
            }
        }
    }
    // ---- epilogue ----
#pragma unroll
    for (int j = 0; j < FJ; ++j) {
        int col = wc + 16 * j + lm;
        float bj = biasT[col];
#pragma unroll
        for (int i = 0; i < FI; ++i) {
            long rbase = rb + wr + 16 * i + quad * 4;
#pragma unroll
            for (int r = 0; r < 4; ++r) {
                float vv = acc[i][j][r] + bj;
                if (RELU) vv = fmaxf(vv, 0.f);
                long o = (rbase + r) * (long)ldc + coff + n0 + col;
                if (OUTSPLIT) ((u32*)(z ? C1v : C0v))[o] = packsplit(vv);
                else          ((float*)(z ? C1v : C0v))[o] = vv;
            }
        }
    }
}

// ---------------------------------------------------------------------------
// k_prep: per pair — denom, v-pool, z-pool, assemble XF/XH (1536 each),
// written in packed-split u32 format for the head GEMMs.
// XF = [vs, poolf, zs(512), poolzf(512)], XH = [vs, poolh, zs, poolzh]
// ---------------------------------------------------------------------------
__global__ __launch_bounds__(256) void k_prep(
    const int* __restrict__ pairIdx, const int* __restrict__ prb,
    const float* __restrict__ dm, const float* __restrict__ v,
    const float* __restrict__ obs,
    u32* __restrict__ XF, u32* __restrict__ XH)
{
    int pv = blockIdx.x, c = threadIdx.x;
    int p = pairIdx[pv];
    u32* xf = XF + (long)pv * 1536;
    u32* xh = XH + (long)pv * 1536;
    if (p < 0) {
        for (int s = 0; s < 6; ++s) { xf[s * 256 + c] = 0u; xh[s * 256 + c] = 0u; }
        return;
    }
    __shared__ float sw[22];
    if (c < 22) sw[c] = dm[p * 22 + c];
    __syncthreads();
    float denf = 0.f, denh = 0.f;
    for (int e = 1; e < 12; ++e)  denf += sw[e];
    for (int e = 12; e < 22; ++e) denh += sw[e];
    denf = 1.f / fmaxf(denf, 1.f);
    denh = 1.f / fmaxf(denh, 1.f);

    long base = prb[pv];
    u32 vs = packsplit(v[base * 256 + c]);
    xf[c] = vs; xh[c] = vs;
    float af = 0.f, ah = 0.f;
    for (int e = 1; e < 12; ++e)  af += sw[e] * v[(base + e) * 256 + c];
    for (int e = 12; e < 22; ++e) ah += sw[e] * v[(base + e) * 256 + c];
    xf[256 + c] = packsplit(af * denf);
    xh[256 + c] = packsplit(ah * denh);
    const float* ob = obs + (long)p * 22 * 512;
    float w0 = sw[0];
    u32 z0 = packsplit(ob[c] * w0);
    u32 z1 = packsplit(ob[256 + c] * w0);
    xf[512 + c] = z0; xh[512 + c] = z0;
    xf[768 + c] = z1; xh[768 + c] = z1;
#pragma unroll
    for (int half = 0; half < 2; ++half) {
        int c2 = c + half * 256;
        float zf = 0.f, zh = 0.f;
        for (int e = 1; e < 12; ++e)  zf += sw[e] * ob[(long)e * 512 + c2];
        for (int e = 12; e < 22; ++e) zh += sw[e] * ob[(long)e * 512 + c2];
        xf[1024 + c2] = packsplit(zf * denf);
        xh[1024 + c2] = packsplit(zh * denh);
    }
}

// ---------------------------------------------------------------------------
// Final: L2 layer fused + logits + argmax + log-softmax + value dot; scatter.
// ---------------------------------------------------------------------------
__global__ __launch_bounds__(128) void k_final(
    const float* __restrict__ g1, const float* __restrict__ vV,
    const float* __restrict__ L2, const float* __restrict__ bL2,
    const float* __restrict__ L3, const float* __restrict__ bL3,
    const float* __restrict__ V2, const float* __restrict__ bV2,
    const int* __restrict__ pairIdx, const int* __restrict__ ps,
    float* __restrict__ out)
{
    int pv = blockIdx.x;
    int p = pairIdx[pv];
    if (p < 0) return;
    int c = threadIdx.x;
    int t = (pv >= ps[1]) + (pv >= ps[2]);

    __shared__ float sg1[256], sg2[128], sval[2];
    const float* g1p = g1 + (long)pv * 256;
    sg1[c] = g1p[c];
    sg1[c + 128] = g1p[c + 128];

    const float* vv = vV + (long)pv * 256;
    const float* v2t = V2 + t * 256;
    float s = vv[c] * v2t[c] + vv[c + 128] * v2t[c + 128];
    for (int off = 32; off; off >>= 1) s += __shfl_down(s, off);
    if ((c & 63) == 0) sval[c >> 6] = s;
    __syncthreads();

    const float* l2 = L2 + (long)t * 256 * 128 + c;
    float a = bL2[t * 128 + c];
#pragma unroll 8
    for (int k = 0; k < 256; ++k) a = fmaf(sg1[k], l2[(long)k * 128], a);
    sg2[c] = fmaxf(a, 0.f);
    __syncthreads();

    if (c < 64) {
        float lg = -3.0e38f;
        if (c < 21) {
            const float* l3t = L3 + (long)t * 128 * 21 + c;
            float acc = bL3[t * 21 + c];
            for (int k = 0; k < 128; ++k) acc = fmaf(sg2[k], l3t[k * 21], acc);
            lg = acc;
        }
        float mv = lg; int mi = (c < 21) ? c : 9999;
        for (int off = 32; off; off >>= 1) {
            float ov = __shfl_down(mv, off);
            int oi = __shfl_down(mi, off);
            if (ov > mv || (ov == mv && oi < mi)) { mv = ov; mi = oi; }
        }
        mv = __shfl(mv, 0); mi = __shfl(mi, 0);
        float e = (c < 21) ? expf(lg - mv) : 0.f;
        for (int off = 32; off; off >>= 1) e += __shfl_down(e, off);
        if (c == 0) {
            out[p] = (float)mi;
            out[NP_ + p] = sval[0] + sval[1] + bV2[t];
            out[2 * NP_ + p] = -logf(e);
        }
    }
}

// ---------------------------------------------------------------------------
extern "C" void kernel_launch(void* const* d_in, const int* in_sizes, int n_in,
                              void* d_out, int out_size, void* d_ws, size_t ws_size,
                              hipStream_t stream)
{
    const float* obs = (const float*)d_in[0];
    const int* hete = (const int*)d_in[1];
    const void* dead = d_in[2];
    const float* W1 = (const float*)d_in[3];  const float* b1 = (const float*)d_in[4];
    const float* W2 = (const float*)d_in[5];  const float* b2 = (const float*)d_in[6];
    const float* WCf = (const float*)d_in[7]; const float* bCf = (const float*)d_in[8];
    const float* WMf = (const float*)d_in[9]; const float* bMf = (const float*)d_in[10];
    const float* WCh = (const float*)d_in[11]; const float* bCh = (const float*)d_in[12];
    const float* WMh = (const float*)d_in[13]; const float* bMh = (const float*)d_in[14];
    const float* L1 = (const float*)d_in[15]; const float* bL1 = (const float*)d_in[16];
    const float* L2 = (const float*)d_in[17]; const float* bL2 = (const float*)d_in[18];
    const float* L3 = (const float*)d_in[19]; const float* bL3 = (const float*)d_in[20];
    const float* V1 = (const float*)d_in[21]; const float* bV1 = (const float*)d_in[22];
    const float* V2 = (const float*)d_in[23]; const float* bV2 = (const float*)d_in[24];
    float* out = (float*)d_out;

    // ---- workspace carve-up ----
    int* wsI = (int*)d_ws;
    int* pairIdx = wsI + 16;
    int* prb = pairIdx + PV_;
    int* rowObs = prb + PV_;
    long fbase = ((16L + PV_ + PV_ + RV_) + 63) & ~63L;
    float* wsF = (float*)d_ws;
    float* dm = wsF + fbase;
    float* cur = dm + NDEAD_;
    // bf16-split fragment-ordered weights (hi/lo per matrix)
    auto allocUS = [&](long K) { u16* p = (u16*)cur; cur += (3L * 256 * K) / 2; return p; };
    u16* W1h = allocUS(512);  u16* W1l = allocUS(512);
    u16* W2h = allocUS(256);  u16* W2l = allocUS(256);
    u16* WCfh = allocUS(512); u16* WCfl = allocUS(512);
    u16* WChh = allocUS(512); u16* WChl = allocUS(512);
    u16* WMfh = allocUS(1536); u16* WMfl = allocUS(1536);
    u16* WMhh = allocUS(1536); u16* WMhl = allocUS(1536);
    u16* L1h = allocUS(512);  u16* L1l = allocUS(512);
    u16* V1h = allocUS(512);  u16* V1l = allocUS(512);
    float* regA = cur;                               // RV_*256 floats
    float* regB = regA + (long)RV_ * 256;            // RV_*256 floats
    u32* h1p = (u32*)regA;                           // packed h1; then XF/XH overlay
    u32* XFp = (u32*)regA;
    u32* XHp = XFp + (long)PV_ * 1536;
    float* v = regB;                                 // fp32; then head overlay
    u32* vCp = (u32*)regB;
    u32* vMp = vCp + (long)PV_ * 512;
    float* g1 = (float*)(vMp + (long)PV_ * 512);
    float* vV = g1 + (long)PV_ * 256;

    // ---- bookkeeping ----
    k_bucket<<<1, 256, 0, stream>>>((const unsigned*)dead, hete, wsI);
    k_deadmask<<<264, 256, 0, stream>>>(dead, wsI, dm);
    k_rowobs<<<266, 256, 0, stream>>>(wsI + 1, wsI + 4, wsI + 8, pairIdx, dm, rowObs);

    // ---- weight conversion (fragment-order + bf16 hi/lo split) ----
    k_wconv<<<3 * 512 / 8, 256, 0, stream>>>(W1, W1h, W1l, 512);
    k_wconv<<<3 * 256 / 8, 256, 0, stream>>>(W2, W2h, W2l, 256);
    k_wconv<<<3 * 512 / 8, 256, 0, stream>>>(WCf, WCfh, WCfl, 512);
    k_wconv<<<3 * 512 / 8, 256, 0, stream>>>(WCh, WChh, WChl, 512);
    k_wconv<<<3 * 1536 / 8, 256, 0, stream>>>(WMf, WMfh, WMfl, 1536);
    k_wconv<<<3 * 1536 / 8, 256, 0, stream>>>(WMh, WMhh, WMhl, 1536);
    k_wconv<<<3 * 512 / 8, 256, 0, stream>>>(L1, L1h, L1l, 512);
    k_wconv<<<3 * 512 / 8, 256, 0, stream>>>(V1, V1h, V1l, 512);

    // ---- phase 1 (entity rows, bucketed by type): block 128x256 ----
    // gemm1: h1p = relu(obs@W1+b1)  [packed out]
    k_mgemm<0, true, true, 4, 8><<<dim3(RV_ / 128, 1, 1), 256, 0, stream>>>(
        obs, obs, 512, rowObs, W1h, W1l, W1h, W1l, b1, b1,
        h1p, h1p, 256, 0, 0, wsI + 9, 512);
    // gemm2: v = h1@W2+b2  [fp32 out, feeds k_prep]
    k_mgemm<1, false, false, 4, 8><<<dim3(RV_ / 128, 1, 1), 256, 0, stream>>>(
        h1p, h1p, 256, nullptr, W2h, W2l, W2h, W2l, b2, b2,
        v, v, 256, 0, 0, wsI + 9, 256);

    // ---- pair prep (writes packed XF/XH) ----
    k_prep<<<PV_, 256, 0, stream>>>(pairIdx, prb, dm, v, obs, XFp, XHp);

    // ---- heads (z-batched pairs): block 64x128 ----
    // H1: vC = [relu(XF@WCf) | relu(XH@WCh)]   K=512, packed out
    k_mgemm<1, true, true, 2, 4><<<dim3(PV_ / 64, 2, 2), 256, 0, stream>>>(
        XFp, XHp, 1536, nullptr, WCfh, WCfl, WChh, WChl, bCf, bCh,
        vCp, vCp, 512, 0, 256, wsI + 5, 512);
    // H2: vM = [relu(XF@WMf) | relu(XH@WMh)]   K=1536, packed out
    k_mgemm<1, true, true, 2, 4><<<dim3(PV_ / 64, 2, 2), 256, 0, stream>>>(
        XFp, XHp, 1536, nullptr, WMfh, WMfl, WMhh, WMhl, bMf, bMh,
        vMp, vMp, 512, 0, 256, wsI + 5, 1536);
    // H3: g1 = relu(vC@L1); vV = relu(vM@V1)   K=512, fp32 out
    k_mgemm<1, true, false, 2, 4><<<dim3(PV_ / 64, 2, 2), 256, 0, stream>>>(
        vCp, vMp, 512, nullptr, L1h, L1l, V1h, V1l, bL1, bV1,
        g1, vV, 256, 0, 0, wsI + 5, 512);

    k_final<<<PV_, 128, 0, stream>>>(g1, vV, L2, bL2, L3, bL3, V2, bV2,
                                     pairIdx, wsI + 4, out);
    (void)in_sizes; (void)n_in; (void)out_size; (void)ws_size;
}

// Round 6
// 619.818 us; speedup vs baseline: 1.1750x; 1.1346x over previous
//
#include <hip/hip_runtime.h>
#include <cstdint>

// Problem constants
#define T_ 64
#define A_ 48
#define NP_ 3072      // T*A pairs
#define E_ 22
#define RAW_ 512
#define H_ 256
#define NACT_ 21
#define NTP_ 3
#define PV_ 3456      // padded virtual pair rows (27 tiles of 128)
#define RV_ 68096     // padded virtual entity rows (532 tiles of 128)
#define NDEAD_ 67584  // NP_*E_

typedef unsigned short u16;
typedef unsigned int u32;
typedef __attribute__((ext_vector_type(8))) short short8;
typedef __attribute__((ext_vector_type(4))) short short4v;
typedef __attribute__((ext_vector_type(4))) float floatx4;

__device__ __forceinline__ u16 f2bf(float x) {
    unsigned u = __float_as_uint(x);
    unsigned r = (u + 0x7FFFu + ((u >> 16) & 1u)) >> 16;
    return (u16)r;
}
__device__ __forceinline__ float bf2f(u16 h) {
    return __uint_as_float(((unsigned)h) << 16);
}
// packed split: high16 = bf16(x), low16 = bf16(x - hi)
__device__ __forceinline__ u32 packsplit(float x) {
    u16 h = f2bf(x);
    u16 l = f2bf(x - bf2f(h));
    return (((u32)h) << 16) | l;
}

// ---------------------------------------------------------------------------
// K_bucket: sniff dead dtype, count pairs per type, build bucketed pair list.
// wsI layout: [0]=mode, [1..3]=cnt, [4..6]=ps, [8..10]=rs,
//             [16..16+PV)=pairIdx, then prb[PV]
// ---------------------------------------------------------------------------
__global__ void k_bucket(const unsigned* __restrict__ deadRaw,
                         const int* __restrict__ hete, int* __restrict__ wsI)
{
    __shared__ int fl[2];
    __shared__ int sc[3], cur[3], sps[3], srs[3];
    int tid = threadIdx.x;
    if (tid < 2) fl[tid] = 0;
    if (tid < 3) { sc[tid] = 0; cur[tid] = 0; }
    __syncthreads();
    int ni = 0, nf = 0;
    for (int i = tid; i < 1024; i += 256) {
        unsigned w = deadRaw[i];
        if (w > 1u) ni = 1;
        if (w != 0u && w != 0x3F800000u) nf = 1;
    }
    if (ni) atomicOr(&fl[0], 1);
    if (nf) atomicOr(&fl[1], 1);
    for (int p = tid; p < NP_; p += 256) atomicAdd(&sc[hete[p]], 1);
    __syncthreads();
    if (tid == 0) {
        int c0 = sc[0], c1 = sc[1], c2 = sc[2];
        int p1 = (c0 + 127) & ~127;
        int p2 = p1 + ((c1 + 127) & ~127);
        sps[0] = 0; sps[1] = p1; sps[2] = p2;
        int r1 = (22 * c0 + 127) & ~127;
        int r2 = r1 + ((22 * c1 + 127) & ~127);
        srs[0] = 0; srs[1] = r1; srs[2] = r2;
        wsI[0] = fl[0] ? (fl[1] ? 2 : 1) : 0;  // 0=int32,1=float32,2=byte
        wsI[1] = c0; wsI[2] = c1; wsI[3] = c2;
        wsI[4] = 0; wsI[5] = p1; wsI[6] = p2;
        wsI[8] = 0; wsI[9] = r1; wsI[10] = r2;
    }
    __syncthreads();
    int* pairIdx = wsI + 16;
    int* prb = pairIdx + PV_;
    for (int pv = tid; pv < PV_; pv += 256) pairIdx[pv] = -1;
    __syncthreads();
    for (int p = tid; p < NP_; p += 256) {
        int t = hete[p];
        int pos = atomicAdd(&cur[t], 1);
        pairIdx[sps[t] + pos] = p;
    }
    for (int pv = tid; pv < PV_; pv += 256) {
        int t = (pv >= sps[1]) + (pv >= sps[2]);
        prb[pv] = srs[t] + 22 * (pv - sps[t]);
    }
}

__global__ void k_deadmask(const void* __restrict__ dead,
                           const int* __restrict__ wsI, float* __restrict__ dm)
{
    int i = blockIdx.x * 256 + threadIdx.x;
    if (i >= NDEAD_) return;
    int mode = wsI[0];
    bool d;
    if (mode == 0)      d = ((const int*)dead)[i] != 0;
    else if (mode == 1) d = ((const float*)dead)[i] != 0.f;
    else                d = ((const unsigned char*)dead)[i] != 0;
    dm[i] = d ? 0.f : 1.f;
}

// rowObs[rv] = obs row index for virtual row, or -1 (padding OR dead -> zero A row)
__global__ void k_rowobs(const int* __restrict__ cnt, const int* __restrict__ ps,
                         const int* __restrict__ rs, const int* __restrict__ pairIdx,
                         const float* __restrict__ dm, int* __restrict__ rowObs)
{
    int rv = blockIdx.x * 256 + threadIdx.x;
    if (rv >= RV_) return;
    int t = (rv >= rs[1]) + (rv >= rs[2]);
    int local = rv - rs[t];
    int out = -1;
    if (local < 22 * cnt[t]) {
        int pl = local / 22;
        int e = local - pl * 22;
        int p = pairIdx[ps[t] + pl];
        if (p >= 0) {
            int oi = p * 22 + e;
            if (dm[oi] != 0.f) out = oi;
        }
    }
    rowObs[rv] = out;
}

// ---------------------------------------------------------------------------
// k_wconv: W[t][k][n] (fp32, n-width 256) -> fragment-ordered bf16 hi/lo:
//   Hi[((t*Kg + g)*256 + n)*8 + e]  with g = k/8, e = k%8, Kg = K/8.
// A wave's B-fragment load (lane l: n = base + (l&15), k-group = g0 + (l>>4))
// reads 4 contiguous 256B segments -> fully coalesced from L2, no LDS needed.
// ---------------------------------------------------------------------------
__global__ void k_wconv(const float* __restrict__ W, u16* __restrict__ Hi,
                        u16* __restrict__ Lo, int K)
{
    int Kg = K >> 3;
    int g = blockIdx.x % Kg;
    int t = blockIdx.x / Kg;
    int n = threadIdx.x;
    const float* w = W + (long)t * K * 256 + n;
    short8 hv, lv;
#pragma unroll
    for (int j = 0; j < 8; ++j) {
        float x = w[(long)(g * 8 + j) * 256];
        u16 hh = f2bf(x);
        hv[j] = (short)hh;
        lv[j] = (short)f2bf(x - bf2f(hh));
    }
    long o = (((long)t * Kg + g) * 256 + n) * 8;
    *(short8*)(Hi + o) = hv;
    *(short8*)(Lo + o) = lv;
}

// ---------------------------------------------------------------------------
// MFMA GEMM via bf16 split. Block = 4 waves (2x2), wave tile FI*16 x FJ*16,
// block tile (FI*32) x (FJ*32). BK=32.
// A: AMODE 0 = fp32 + row-gather + mask (converted in-loop);
//    AMODE 1 = packed-split u32. A staged in LDS (hi/lo shorts, padded).
// B: fragment-ordered bf16 hi/lo, read straight from L2 (coalesced), no LDS.
// NTERM: 3 = full bf16x3 split (logit path); 1 = plain bf16 (value path).
// OUTSPLIT: write C packed-split u32; else fp32.
// Layouts (m89/m120): A[m=lane&15][k=quad*8+j], B[k=quad*8+j][n=lane&15],
// D col=lane&15 row=quad*4+reg.
// ---------------------------------------------------------------------------
#define AST 40  // LDS row stride in shorts (32 k + 8 pad)
template<int AMODE, bool RELU, bool OUTSPLIT, int FI, int FJ, int NTERM>
__global__ __launch_bounds__(256) void k_mgemm(
    const void* __restrict__ A0v, const void* __restrict__ A1v, int lda,
    const int* __restrict__ rowIdx,
    const u16* __restrict__ Bh0, const u16* __restrict__ Bl0,
    const u16* __restrict__ Bh1, const u16* __restrict__ Bl1,
    const float* __restrict__ bias0, const float* __restrict__ bias1,
    void* __restrict__ C0v, void* __restrict__ C1v, int ldc,
    int coff0, int coff1,
    const int* __restrict__ starts, int K)
{
    constexpr int R = FI * 32;                 // block rows
    __shared__ short Ah[R * AST];
    __shared__ short Al[(NTERM == 3) ? (R * AST) : 8];

    const int tid = threadIdx.x;
    const int z = blockIdx.z;
    const void* Av = z ? A1v : A0v;
    const u16* Bhi = z ? Bh1 : Bh0;
    const u16* Blo = z ? Bl1 : Bl0;
    const float* bias = z ? bias1 : bias0;
    const int coff = z ? coff1 : coff0;

    const long rb = (long)blockIdx.x * R;
    const int n0 = blockIdx.y * (FJ * 32);
    const int t = (rb >= starts[0]) + (rb >= starts[1]);
    const int Kg = K >> 3;
    const float* biasT = bias + (long)t * 256 + n0;

    // wave tiling
    const int wave = tid >> 6;
    const int lane = tid & 63;
    const int wr = (wave >> 1) * (FI * 16);
    const int wc = (wave & 1) * (FJ * 16);
    const int lm = lane & 15;
    const int quad = lane >> 4;
    // fragment-ordered B base for this wave/lane
    const u16* bwh = Bhi + (((long)t * Kg + quad) * 256 + n0 + wc + lm) * 8;
    const u16* bwl = Blo + (((long)t * Kg + quad) * 256 + n0 + wc + lm) * 8;

    // ---- A loader setup ----
    const int ar0 = tid >> 3;           // 0..31  (AMODE 0, 32 rows/iter)
    const int ac0 = (tid & 7) * 4;
    const int ar1 = tid >> 2;           // 0..63  (AMODE 1, 64 rows/iter)
    const int ac1 = (tid & 3) * 8;
    long arow[4 > FI ? 4 : FI]; float amask[4 > FI ? 4 : FI];
    if (AMODE == 0) {
#pragma unroll
        for (int it = 0; it < FI; ++it) {
            int r = 32 * it + ar0;
            int i0 = rowIdx[rb + r];
            amask[it] = (i0 < 0) ? 0.f : 1.f;
            arow[it] = (i0 < 0) ? 0 : (long)i0 * lda;
        }
    } else {
#pragma unroll
        for (int it = 0; it < FI / 2; ++it)
            arow[it] = (rb + 64 * it + ar1) * (long)lda;
    }

    floatx4 acc[FI][FJ];
#pragma unroll
    for (int i = 0; i < FI; ++i)
#pragma unroll
        for (int j = 0; j < FJ; ++j) acc[i][j] = (floatx4){0.f, 0.f, 0.f, 0.f};

    for (int k0 = 0; k0 < K; k0 += 32) {
        // ---- stage A tile in LDS ----
        if (AMODE == 0) {
            const float* A = (const float*)Av;
            float4 av[FI];
#pragma unroll
            for (int it = 0; it < FI; ++it)
                av[it] = *(const float4*)(A + arow[it] + k0 + ac0);
            __syncthreads();
#pragma unroll
            for (int it = 0; it < FI; ++it) {
                float xs[4] = {av[it].x, av[it].y, av[it].z, av[it].w};
                short4v hv, lv;
#pragma unroll
                for (int e = 0; e < 4; ++e) {
                    float x = xs[e] * amask[it];
                    u16 hh = f2bf(x);
                    hv[e] = (short)hh;
                    lv[e] = (short)f2bf(x - bf2f(hh));
                }
                int r = 32 * it + ar0;
                *(short4v*)&Ah[r * AST + ac0] = hv;
                if (NTERM == 3) *(short4v*)&Al[r * AST + ac0] = lv;
            }
        } else {
            const u32* A = (const u32*)Av;
            uint4 u0[FI / 2], u1[FI / 2];
#pragma unroll
            for (int it = 0; it < FI / 2; ++it) {
                u0[it] = *(const uint4*)(A + arow[it] + k0 + ac1);
                u1[it] = *(const uint4*)(A + arow[it] + k0 + ac1 + 4);
            }
            __syncthreads();
#pragma unroll
            for (int it = 0; it < FI / 2; ++it) {
                u32 w[8] = {u0[it].x, u0[it].y, u0[it].z, u0[it].w,
                            u1[it].x, u1[it].y, u1[it].z, u1[it].w};
                short8 hv, lv;
#pragma unroll
                for (int e = 0; e < 8; ++e) {
                    hv[e] = (short)(w[e] >> 16);
                    lv[e] = (short)(w[e] & 0xFFFFu);
                }
                int r = 64 * it + ar1;
                *(short8*)&Ah[r * AST + ac1] = hv;
                if (NTERM == 3) *(short8*)&Al[r * AST + ac1] = lv;
            }
        }
        __syncthreads();

        // ---- B fragments from L2 (coalesced, contiguous per k-group) ----
        const long gb = ((long)(k0 >> 3)) * 2048;   // (k0/8)*256*8 shorts
        short8 fbh[FJ], fbl[FJ];
#pragma unroll
        for (int j = 0; j < FJ; ++j) {
            fbh[j] = *(const short8*)(bwh + gb + j * 128);
            if (NTERM == 3) fbl[j] = *(const short8*)(bwl + gb + j * 128);
        }
        // ---- A fragments from LDS ----
        short8 fah[FI], fal[FI];
#pragma unroll
        for (int i = 0; i < FI; ++i) {
            int m = wr + 16 * i + lm;
            fah[i] = *(const short8*)&Ah[m * AST + quad * 8];
            if (NTERM == 3) fal[i] = *(const short8*)&Al[m * AST + quad * 8];
        }
        // ---- MFMA ----
#pragma unroll
        for (int j = 0; j < FJ; ++j) {
#pragma unroll
            for (int i = 0; i < FI; ++i) {
                acc[i][j] = __builtin_amdgcn_mfma_f32_16x16x32_bf16(fah[i], fbh[j], acc[i][j], 0, 0, 0);
                if (NTERM == 3) {
                    acc[i][j] = __builtin_amdgcn_mfma_f32_16x16x32_bf16(fal[i], fbh[j], acc[i][j], 0, 0, 0);
                    acc[i][j] = __builtin_amdgcn_mfma_f32_16x16x32_bf16(fah[i], fbl[j], acc[i][j], 0, 0, 0);
                }
            }
        }
    }
    // ---- epilogue ----
#pragma unroll
    for (int j = 0; j < FJ; ++j) {
        int col = wc + 16 * j + lm;
        float bj = biasT[col];
#pragma unroll
        for (int i = 0; i < FI; ++i) {
            long rbase = rb + wr + 16 * i + quad * 4;
#pragma unroll
            for (int r = 0; r < 4; ++r) {
                float vv = acc[i][j][r] + bj;
                if (RELU) vv = fmaxf(vv, 0.f);
                long o = (rbase + r) * (long)ldc + coff + n0 + col;
                if (OUTSPLIT) ((u32*)(z ? C1v : C0v))[o] = packsplit(vv);
                else          ((float*)(z ? C1v : C0v))[o] = vv;
            }
        }
    }
}

// ---------------------------------------------------------------------------
// k_prep: per pair — denom, v-pool, z-pool, assemble XF/XH (1536 each),
// written in packed-split u32 format for the head GEMMs.
// XF = [vs, poolf, zs(512), poolzf(512)], XH = [vs, poolh, zs, poolzh]
// ---------------------------------------------------------------------------
__global__ __launch_bounds__(256) void k_prep(
    const int* __restrict__ pairIdx, const int* __restrict__ prb,
    const float* __restrict__ dm, const float* __restrict__ v,
    const float* __restrict__ obs,
    u32* __restrict__ XF, u32* __restrict__ XH)
{
    int pv = blockIdx.x, c = threadIdx.x;
    int p = pairIdx[pv];
    u32* xf = XF + (long)pv * 1536;
    u32* xh = XH + (long)pv * 1536;
    if (p < 0) {
        for (int s = 0; s < 6; ++s) { xf[s * 256 + c] = 0u; xh[s * 256 + c] = 0u; }
        return;
    }
    __shared__ float sw[22];
    if (c < 22) sw[c] = dm[p * 22 + c];
    __syncthreads();
    float denf = 0.f, denh = 0.f;
    for (int e = 1; e < 12; ++e)  denf += sw[e];
    for (int e = 12; e < 22; ++e) denh += sw[e];
    denf = 1.f / fmaxf(denf, 1.f);
    denh = 1.f / fmaxf(denh, 1.f);

    long base = prb[pv];
    u32 vs = packsplit(v[base * 256 + c]);
    xf[c] = vs; xh[c] = vs;
    float af = 0.f, ah = 0.f;
    for (int e = 1; e < 12; ++e)  af += sw[e] * v[(base + e) * 256 + c];
    for (int e = 12; e < 22; ++e) ah += sw[e] * v[(base + e) * 256 + c];
    xf[256 + c] = packsplit(af * denf);
    xh[256 + c] = packsplit(ah * denh);
    const float* ob = obs + (long)p * 22 * 512;
    float w0 = sw[0];
    u32 z0 = packsplit(ob[c] * w0);
    u32 z1 = packsplit(ob[256 + c] * w0);
    xf[512 + c] = z0; xh[512 + c] = z0;
    xf[768 + c] = z1; xh[768 + c] = z1;
#pragma unroll
    for (int half = 0; half < 2; ++half) {
        int c2 = c + half * 256;
        float zf = 0.f, zh = 0.f;
        for (int e = 1; e < 12; ++e)  zf += sw[e] * ob[(long)e * 512 + c2];
        for (int e = 12; e < 22; ++e) zh += sw[e] * ob[(long)e * 512 + c2];
        xf[1024 + c2] = packsplit(zf * denf);
        xh[1024 + c2] = packsplit(zh * denh);
    }
}

// ---------------------------------------------------------------------------
// Final: L2 layer fused + logits + argmax + log-softmax + value dot; scatter.
// ---------------------------------------------------------------------------
__global__ __launch_bounds__(128) void k_final(
    const float* __restrict__ g1, const float* __restrict__ vV,
    const float* __restrict__ L2, const float* __restrict__ bL2,
    const float* __restrict__ L3, const float* __restrict__ bL3,
    const float* __restrict__ V2, const float* __restrict__ bV2,
    const int* __restrict__ pairIdx, const int* __restrict__ ps,
    float* __restrict__ out)
{
    int pv = blockIdx.x;
    int p = pairIdx[pv];
    if (p < 0) return;
    int c = threadIdx.x;
    int t = (pv >= ps[1]) + (pv >= ps[2]);

    __shared__ float sg1[256], sg2[128], sval[2];
    const float* g1p = g1 + (long)pv * 256;
    sg1[c] = g1p[c];
    sg1[c + 128] = g1p[c + 128];

    const float* vv = vV + (long)pv * 256;
    const float* v2t = V2 + t * 256;
    float s = vv[c] * v2t[c] + vv[c + 128] * v2t[c + 128];
    for (int off = 32; off; off >>= 1) s += __shfl_down(s, off);
    if ((c & 63) == 0) sval[c >> 6] = s;
    __syncthreads();

    const float* l2 = L2 + (long)t * 256 * 128 + c;
    float a = bL2[t * 128 + c];
#pragma unroll 8
    for (int k = 0; k < 256; ++k) a = fmaf(sg1[k], l2[(long)k * 128], a);
    sg2[c] = fmaxf(a, 0.f);
    __syncthreads();

    if (c < 64) {
        float lg = -3.0e38f;
        if (c < 21) {
            const float* l3t = L3 + (long)t * 128 * 21 + c;
            float acc = bL3[t * 21 + c];
            for (int k = 0; k < 128; ++k) acc = fmaf(sg2[k], l3t[k * 21], acc);
            lg = acc;
        }
        float mv = lg; int mi = (c < 21) ? c : 9999;
        for (int off = 32; off; off >>= 1) {
            float ov = __shfl_down(mv, off);
            int oi = __shfl_down(mi, off);
            if (ov > mv || (ov == mv && oi < mi)) { mv = ov; mi = oi; }
        }
        mv = __shfl(mv, 0); mi = __shfl(mi, 0);
        float e = (c < 21) ? expf(lg - mv) : 0.f;
        for (int off = 32; off; off >>= 1) e += __shfl_down(e, off);
        if (c == 0) {
            out[p] = (float)mi;
            out[NP_ + p] = sval[0] + sval[1] + bV2[t];
            out[2 * NP_ + p] = -logf(e);
        }
    }
}

// ---------------------------------------------------------------------------
extern "C" void kernel_launch(void* const* d_in, const int* in_sizes, int n_in,
                              void* d_out, int out_size, void* d_ws, size_t ws_size,
                              hipStream_t stream)
{
    const float* obs = (const float*)d_in[0];
    const int* hete = (const int*)d_in[1];
    const void* dead = d_in[2];
    const float* W1 = (const float*)d_in[3];  const float* b1 = (const float*)d_in[4];
    const float* W2 = (const float*)d_in[5];  const float* b2 = (const float*)d_in[6];
    const float* WCf = (const float*)d_in[7]; const float* bCf = (const float*)d_in[8];
    const float* WMf = (const float*)d_in[9]; const float* bMf = (const float*)d_in[10];
    const float* WCh = (const float*)d_in[11]; const float* bCh = (const float*)d_in[12];
    const float* WMh = (const float*)d_in[13]; const float* bMh = (const float*)d_in[14];
    const float* L1 = (const float*)d_in[15]; const float* bL1 = (const float*)d_in[16];
    const float* L2 = (const float*)d_in[17]; const float* bL2 = (const float*)d_in[18];
    const float* L3 = (const float*)d_in[19]; const float* bL3 = (const float*)d_in[20];
    const float* V1 = (const float*)d_in[21]; const float* bV1 = (const float*)d_in[22];
    const float* V2 = (const float*)d_in[23]; const float* bV2 = (const float*)d_in[24];
    float* out = (float*)d_out;

    // ---- workspace carve-up ----
    int* wsI = (int*)d_ws;
    int* pairIdx = wsI + 16;
    int* prb = pairIdx + PV_;
    int* rowObs = prb + PV_;
    long fbase = ((16L + PV_ + PV_ + RV_) + 63) & ~63L;
    float* wsF = (float*)d_ws;
    float* dm = wsF + fbase;
    float* cur = dm + NDEAD_;
    // bf16-split fragment-ordered weights (hi/lo per matrix)
    auto allocUS = [&](long K) { u16* p = (u16*)cur; cur += (3L * 256 * K) / 2; return p; };
    u16* W1h = allocUS(512);  u16* W1l = allocUS(512);
    u16* W2h = allocUS(256);  u16* W2l = allocUS(256);
    u16* WCfh = allocUS(512); u16* WCfl = allocUS(512);
    u16* WChh = allocUS(512); u16* WChl = allocUS(512);
    u16* WMfh = allocUS(1536); u16* WMfl = allocUS(1536);
    u16* WMhh = allocUS(1536); u16* WMhl = allocUS(1536);
    u16* L1h = allocUS(512);  u16* L1l = allocUS(512);
    u16* V1h = allocUS(512);  u16* V1l = allocUS(512);
    float* regA = cur;                               // RV_*256 floats
    float* regB = regA + (long)RV_ * 256;            // RV_*256 floats
    u32* h1p = (u32*)regA;                           // packed h1; then XF/XH overlay
    u32* XFp = (u32*)regA;
    u32* XHp = XFp + (long)PV_ * 1536;
    float* v = regB;                                 // fp32; then head overlay
    u32* vCp = (u32*)regB;
    u32* vMp = vCp + (long)PV_ * 512;
    float* g1 = (float*)(vMp + (long)PV_ * 512);
    float* vV = g1 + (long)PV_ * 256;

    // ---- bookkeeping ----
    k_bucket<<<1, 256, 0, stream>>>((const unsigned*)dead, hete, wsI);
    k_deadmask<<<264, 256, 0, stream>>>(dead, wsI, dm);
    k_rowobs<<<266, 256, 0, stream>>>(wsI + 1, wsI + 4, wsI + 8, pairIdx, dm, rowObs);

    // ---- weight conversion (fragment-order + bf16 hi/lo split) ----
    k_wconv<<<3 * 512 / 8, 256, 0, stream>>>(W1, W1h, W1l, 512);
    k_wconv<<<3 * 256 / 8, 256, 0, stream>>>(W2, W2h, W2l, 256);
    k_wconv<<<3 * 512 / 8, 256, 0, stream>>>(WCf, WCfh, WCfl, 512);
    k_wconv<<<3 * 512 / 8, 256, 0, stream>>>(WCh, WChh, WChl, 512);
    k_wconv<<<3 * 1536 / 8, 256, 0, stream>>>(WMf, WMfh, WMfl, 1536);
    k_wconv<<<3 * 1536 / 8, 256, 0, stream>>>(WMh, WMhh, WMhl, 1536);
    k_wconv<<<3 * 512 / 8, 256, 0, stream>>>(L1, L1h, L1l, 512);
    k_wconv<<<3 * 512 / 8, 256, 0, stream>>>(V1, V1h, V1l, 512);

    // ---- phase 1 (entity rows, bucketed by type): block 128x128, FJ=4 ----
    // gemm1: h1p = relu(obs@W1+b1)  [packed out, 3-term]
    k_mgemm<0, true, true, 4, 4, 3><<<dim3(RV_ / 128, 2, 1), 256, 0, stream>>>(
        obs, obs, 512, rowObs, W1h, W1l, W1h, W1l, b1, b1,
        h1p, h1p, 256, 0, 0, wsI + 9, 512);
    // gemm2: v = h1@W2+b2  [fp32 out, 3-term]
    k_mgemm<1, false, false, 4, 4, 3><<<dim3(RV_ / 128, 2, 1), 256, 0, stream>>>(
        h1p, h1p, 256, nullptr, W2h, W2l, W2h, W2l, b2, b2,
        v, v, 256, 0, 0, wsI + 9, 256);

    // ---- pair prep (writes packed XF/XH) ----
    k_prep<<<PV_, 256, 0, stream>>>(pairIdx, prb, dm, v, obs, XFp, XHp);

    // ---- heads (64-row tiles) ----
    // H1 (logit path, 3-term): vC = [relu(XF@WCf) | relu(XH@WCh)]  K=512
    k_mgemm<1, true, true, 2, 4, 3><<<dim3(PV_ / 64, 2, 2), 256, 0, stream>>>(
        XFp, XHp, 1536, nullptr, WCfh, WCfl, WChh, WChl, bCf, bCh,
        vCp, vCp, 512, 0, 256, wsI + 5, 512);
    // H2 (value path, 1-term): vM = [relu(XF@WMf) | relu(XH@WMh)]  K=1536
    k_mgemm<1, true, true, 2, 4, 1><<<dim3(PV_ / 64, 2, 2), 256, 0, stream>>>(
        XFp, XHp, 1536, nullptr, WMfh, WMfh, WMhh, WMhh, bMf, bMh,
        vMp, vMp, 512, 0, 256, wsI + 5, 1536);
    // H3a (logit path, 3-term): g1 = relu(vC@L1+bL1)  K=512
    k_mgemm<1, true, false, 2, 4, 3><<<dim3(PV_ / 64, 2, 1), 256, 0, stream>>>(
        vCp, vCp, 512, nullptr, L1h, L1l, L1h, L1l, bL1, bL1,
        g1, g1, 256, 0, 0, wsI + 5, 512);
    // H3b (value path, 1-term): vV = relu(vM@V1+bV1)  K=512
    k_mgemm<1, true, false, 2, 4, 1><<<dim3(PV_ / 64, 2, 1), 256, 0, stream>>>(
        vMp, vMp, 512, nullptr, V1h, V1h, V1h, V1h, bV1, bV1,
        vV, vV, 256, 0, 0, wsI + 5, 512);

    k_final<<<PV_, 128, 0, stream>>>(g1, vV, L2, bL2, L3, bL3, V2, bV2,
                                     pairIdx, wsI + 4, out);
    (void)in_sizes; (void)n_in; (void)out_size; (void)ws_size;
}